// Round 1
// baseline (271.104 us; speedup 1.0000x reference)
//
#include <hip/hip_runtime.h>

#define S_LEN 2048
#define DMODEL 1024
#define NHEAD 16
#define DHEAD 64
#define BATCH 2
#define BH_TOT (BATCH * NHEAD)   // 32
#define TOK (BATCH * S_LEN)      // 4096
#define NQKV (3 * DMODEL)        // 3072

typedef float  f32x4  __attribute__((ext_vector_type(4)));
typedef __bf16 bf16x8 __attribute__((ext_vector_type(8)));
typedef __bf16 bf16x4 __attribute__((ext_vector_type(4)));
typedef __bf16 bf16x2 __attribute__((ext_vector_type(2)));

typedef __attribute__((address_space(1))) void* as1_ptr;
typedef __attribute__((address_space(3))) void* as3_ptr;

__device__ __forceinline__ void gl2lds16(const void* g, void* l) {
  // async global->LDS, 16B per lane; LDS dest must be wave-uniform base + lane*16
  __builtin_amdgcn_global_load_lds((as1_ptr)(void*)g, (as3_ptr)l, 16, 0, 0);
}

__device__ __forceinline__ f32x4 mfma_bf16(bf16x8 a, bf16x8 b, f32x4 c) {
  return __builtin_amdgcn_mfma_f32_16x16x32_bf16(a, b, c, 0, 0, 0);
}

// ---------------------------------------------------------------- convert f32 -> bf16
__global__ __launch_bounds__(256) void cvt_kernel(const float* __restrict__ src,
                                                  __bf16* __restrict__ dst, int n) {
  const int i = (blockIdx.x * 256 + threadIdx.x) * 4;
  if (i >= n) return;
  const f32x4 v = *(const f32x4*)(src + i);
  bf16x4 o;
  o[0] = (__bf16)v[0]; o[1] = (__bf16)v[1]; o[2] = (__bf16)v[2]; o[3] = (__bf16)v[3];
  *(bf16x4*)(dst + i) = o;
}

// ---------------------------------------------------------------- 128x128 bf16 GEMM mainloop
// C[128x128] = A_tile[128xK] * B_tile[128xK]^T  (both row-major [row][k], bf16)
__device__ __forceinline__ void gemm_tile_128(const __bf16* __restrict__ A,
                                              const __bf16* __restrict__ Bw,
                                              const int Kd, const int tileM, const int tileN,
                                              __bf16* As, __bf16* Bs, f32x4 acc[4][4]) {
  const int t    = threadIdx.x;
  const int lane = t & 63;
  const int wave = t >> 6;
  const int quad = lane >> 4;
  const int c    = lane & 15;
  const int wm   = (wave >> 1) << 6;
  const int wn   = (wave & 1) << 6;

  // staging: 512 x 16B units per 8KB tile; unit u -> row=u>>2, kchunk=u&3
  const int u0 = t, u1 = t + 256;
  const __bf16* gA0 = A  + (size_t)(tileM + (u0 >> 2)) * Kd + (u0 & 3) * 8;
  const __bf16* gA1 = A  + (size_t)(tileM + (u1 >> 2)) * Kd + (u1 & 3) * 8;
  const __bf16* gB0 = Bw + (size_t)(tileN + (u0 >> 2)) * Kd + (u0 & 3) * 8;
  const __bf16* gB1 = Bw + (size_t)(tileN + (u1 >> 2)) * Kd + (u1 & 3) * 8;
  __bf16* lA0 = As + u0 * 8; __bf16* lA1 = As + u1 * 8;
  __bf16* lB0 = Bs + u0 * 8; __bf16* lB1 = Bs + u1 * 8;

  for (int k0 = 0; k0 < Kd; k0 += 32) {
    gl2lds16(gA0 + k0, lA0);
    gl2lds16(gA1 + k0, lA1);
    gl2lds16(gB0 + k0, lB0);
    gl2lds16(gB1 + k0, lB1);
    __syncthreads();
    bf16x8 af[4], bfr[4];
#pragma unroll
    for (int mt = 0; mt < 4; ++mt)
      af[mt] = *(const bf16x8*)(As + (wm + mt * 16 + c) * 32 + quad * 8);
#pragma unroll
    for (int nt = 0; nt < 4; ++nt)
      bfr[nt] = *(const bf16x8*)(Bs + (wn + nt * 16 + c) * 32 + quad * 8);
#pragma unroll
    for (int mt = 0; mt < 4; ++mt)
#pragma unroll
      for (int nt = 0; nt < 4; ++nt)
        acc[mt][nt] = mfma_bf16(af[mt], bfr[nt], acc[mt][nt]);
    __syncthreads();
  }
}

// ---------------------------------------------------------------- QKV projection
__global__ __launch_bounds__(256) void gemm_qkv_kernel(const __bf16* __restrict__ xb,
                                                       const __bf16* __restrict__ Wb,
                                                       const float* __restrict__ bias,
                                                       __bf16* __restrict__ Qb,
                                                       __bf16* __restrict__ Kb,
                                                       __bf16* __restrict__ Vb) {
  __shared__ __align__(16) __bf16 As[128 * 32];
  __shared__ __align__(16) __bf16 Bs[128 * 32];
  f32x4 acc[4][4];
#pragma unroll
  for (int i = 0; i < 4; ++i)
#pragma unroll
    for (int j = 0; j < 4; ++j) acc[i][j] = (f32x4){0.f, 0.f, 0.f, 0.f};

  const int tileM = blockIdx.y * 128;
  const int tileN = blockIdx.x * 128;
  gemm_tile_128(xb, Wb, DMODEL, tileM, tileN, As, Bs, acc);

  const int t = threadIdx.x;
  const int lane = t & 63, wave = t >> 6;
  const int quad = lane >> 4, c = lane & 15;
  const int wm = (wave >> 1) << 6, wn = (wave & 1) << 6;

#pragma unroll
  for (int nt = 0; nt < 4; ++nt) {
    const int col = tileN + wn + nt * 16 + c;
    const float bv = bias[col];
    const int which = col >> 10;         // 0=q,1=k,2=v
    const int h  = (col >> 6) & 15;
    const int dh = col & 63;
    __bf16* dst = (which == 0) ? Qb : ((which == 1) ? Kb : Vb);
#pragma unroll
    for (int mt = 0; mt < 4; ++mt) {
#pragma unroll
      for (int r = 0; r < 4; ++r) {
        const int row = tileM + wm + mt * 16 + quad * 4 + r;  // token id
        const int bb = row >> 11;
        const int ss = row & (S_LEN - 1);
        dst[(((size_t)(bb * NHEAD + h)) * S_LEN + ss) * DHEAD + dh] =
            (__bf16)(acc[mt][nt][r] + bv);
      }
    }
  }
}

// ---------------------------------------------------------------- output projection
__global__ __launch_bounds__(256) void gemm_out_kernel(const __bf16* __restrict__ AOb,
                                                       const __bf16* __restrict__ Wb,
                                                       const float* __restrict__ bout,
                                                       float* __restrict__ out) {
  __shared__ __align__(16) __bf16 As[128 * 32];
  __shared__ __align__(16) __bf16 Bs[128 * 32];
  f32x4 acc[4][4];
#pragma unroll
  for (int i = 0; i < 4; ++i)
#pragma unroll
    for (int j = 0; j < 4; ++j) acc[i][j] = (f32x4){0.f, 0.f, 0.f, 0.f};

  const int tileM = blockIdx.y * 128;
  const int tileN = blockIdx.x * 128;
  gemm_tile_128(AOb, Wb, DMODEL, tileM, tileN, As, Bs, acc);

  const int t = threadIdx.x;
  const int lane = t & 63, wave = t >> 6;
  const int quad = lane >> 4, c = lane & 15;
  const int wm = (wave >> 1) << 6, wn = (wave & 1) << 6;

#pragma unroll
  for (int nt = 0; nt < 4; ++nt) {
    const int col = tileN + wn + nt * 16 + c;
    const float bv = bout[col];
#pragma unroll
    for (int mt = 0; mt < 4; ++mt) {
#pragma unroll
      for (int r = 0; r < 4; ++r) {
        const int row = tileM + wm + mt * 16 + quad * 4 + r;
        out[(size_t)row * DMODEL + col] = acc[mt][nt][r] + bv;
      }
    }
  }
}

// ---------------------------------------------------------------- partial interleaved RoPE (in place on Q and K)
__global__ __launch_bounds__(256) void rope_kernel(__bf16* __restrict__ Qb, __bf16* __restrict__ Kb) {
  const int idx = blockIdx.x * 256 + threadIdx.x;   // [0, 2*32*2048*16)
  const int j  = idx & 15;                          // rotation pair 0..15 (dims 2j, 2j+1)
  const int s  = (idx >> 4) & (S_LEN - 1);
  const int bh = (idx >> 15) & (BH_TOT - 1);
  __bf16* base = (idx >> 20) ? Kb : Qb;
  bf16x2* p = (bf16x2*)(base + ((size_t)bh * S_LEN + s) * DHEAD) + j;
  bf16x2 v = *p;
  const float x1 = (float)v[0];
  const float x2 = (float)v[1];
  // inv_freq[j] = 10000^(-j/16)
  const float LOG2_10000 = 13.287712379549449f;
  const float inv = exp2f(-(float)j * (LOG2_10000 / 16.0f));
  const float ang = (float)s * inv;
  float sn, cs;
  sincosf(ang, &sn, &cs);
  bf16x2 o;
  o[0] = (__bf16)(x1 * cs - x2 * sn);
  o[1] = (__bf16)(x2 * cs + x1 * sn);
  *p = o;
}

// ---------------------------------------------------------------- V transpose: [bh][s][d] -> [bh][d][s]
__global__ __launch_bounds__(256) void vtrans_kernel(const __bf16* __restrict__ Vb,
                                                     __bf16* __restrict__ Vtb) {
  __shared__ __align__(16) __bf16 T[64 * 72];
  const int bh = blockIdx.x >> 5;
  const int st = (blockIdx.x & 31) * 64;
  const int t = threadIdx.x;
#pragma unroll
  for (int i = 0; i < 2; ++i) {
    const int u = t + i * 256;
    const int sl = u >> 3, dc = u & 7;
    bf16x8 v = *(const bf16x8*)(Vb + ((size_t)bh * S_LEN + st + sl) * DHEAD + dc * 8);
#pragma unroll
    for (int jj = 0; jj < 8; ++jj) T[(dc * 8 + jj) * 72 + sl] = v[jj];
  }
  __syncthreads();
#pragma unroll
  for (int i = 0; i < 2; ++i) {
    const int u = t + i * 256;
    const int d = u >> 3, sc = u & 7;
    *(bf16x8*)(Vtb + ((size_t)bh * DHEAD + d) * S_LEN + st + sc * 8) =
        *(const bf16x8*)(T + d * 72 + sc * 8);
  }
}

// ---------------------------------------------------------------- flash attention
// grid: x = q-tile (32), y = bh (32); block 256 = 4 waves, each wave owns 16 q-rows
__global__ __launch_bounds__(256) void attn_kernel(const __bf16* __restrict__ Qb,
                                                   const __bf16* __restrict__ Kb,
                                                   const __bf16* __restrict__ Vtb,
                                                   __bf16* __restrict__ AOb) {
  __shared__ __align__(16) __bf16 Ks[64 * 72];    // [key][d]
  __shared__ __align__(16) __bf16 Vts[64 * 72];   // [d][key]
  __shared__ __align__(16) __bf16 Ps[4][16 * 72]; // per-wave P strip [q][key]

  const int qt = blockIdx.x;
  const int bh = blockIdx.y;
  const int b = bh >> 4, h = bh & 15;
  const int t = threadIdx.x, wave = t >> 6, lane = t & 63;
  const int quad = lane >> 4, c = lane & 15;

  const size_t head = (size_t)bh * S_LEN * DHEAD;
  const int q0 = qt * 64;

  // Q A-fragments held in registers for the whole kernel: A[m=c][k=quad*8+j (+32)]
  bf16x8 aq0, aq1;
  {
    const __bf16* qp = Qb + head + (size_t)(q0 + wave * 16 + c) * DHEAD + quad * 8;
    aq0 = *(const bf16x8*)qp;
    aq1 = *(const bf16x8*)(qp + 32);
  }

  float m_run[4], l_run[4];
  f32x4 o[4];
#pragma unroll
  for (int r = 0; r < 4; ++r) { m_run[r] = -1e30f; l_run[r] = 0.f; }
#pragma unroll
  for (int dt = 0; dt < 4; ++dt) o[dt] = (f32x4){0.f, 0.f, 0.f, 0.f};

  for (int kb = 0; kb < S_LEN / 64; ++kb) {
    const int k0 = kb * 64;
    // stage K-tile [64 keys][64 d] and Vt-tile [64 d][64 keys]
#pragma unroll
    for (int i = 0; i < 2; ++i) {
      const int u = t + i * 256;
      const int row = u >> 3, cc = u & 7;
      *(bf16x8*)(Ks + row * 72 + cc * 8) =
          *(const bf16x8*)(Kb + head + (size_t)(k0 + row) * DHEAD + cc * 8);
      *(bf16x8*)(Vts + row * 72 + cc * 8) =
          *(const bf16x8*)(Vtb + ((size_t)bh * DHEAD + row) * S_LEN + k0 + cc * 8);
    }
    __syncthreads();

    // S-strip: 16 q-rows x 64 keys
    f32x4 sc4[4];
#pragma unroll
    for (int nt = 0; nt < 4; ++nt) {
      const __bf16* kr = Ks + (nt * 16 + c) * 72 + quad * 8;
      bf16x8 b0 = *(const bf16x8*)kr;
      bf16x8 b1 = *(const bf16x8*)(kr + 32);
      f32x4 z = (f32x4){0.f, 0.f, 0.f, 0.f};
      z = mfma_bf16(aq0, b0, z);
      z = mfma_bf16(aq1, b1, z);
      sc4[nt] = z;
    }

    // online softmax (lane holds rows quad*4+r, key col = nt*16+c)
#pragma unroll
    for (int r = 0; r < 4; ++r) {
      float mx = fmaxf(fmaxf(sc4[0][r], sc4[1][r]), fmaxf(sc4[2][r], sc4[3][r])) * 0.125f;
#pragma unroll
      for (int off = 1; off < 16; off <<= 1) mx = fmaxf(mx, __shfl_xor(mx, off));
      const float m_new = fmaxf(m_run[r], mx);
      const float alpha = __expf(m_run[r] - m_new);
      float rs = 0.f;
#pragma unroll
      for (int nt = 0; nt < 4; ++nt) {
        const float p = __expf(sc4[nt][r] * 0.125f - m_new);
        rs += p;
        Ps[wave][(quad * 4 + r) * 72 + nt * 16 + c] = (__bf16)p;  // C-layout -> row-major P
      }
#pragma unroll
      for (int off = 1; off < 16; off <<= 1) rs += __shfl_xor(rs, off);
      l_run[r] = l_run[r] * alpha + rs;
      m_run[r] = m_new;
#pragma unroll
      for (int dt = 0; dt < 4; ++dt) o[dt][r] = o[dt][r] * alpha;
    }

    // O += P * V   (A = P from LDS, B = V via Vts[d][key])
    {
      const __bf16* pr = &Ps[wave][c * 72 + quad * 8];
      bf16x8 ap0 = *(const bf16x8*)pr;
      bf16x8 ap1 = *(const bf16x8*)(pr + 32);
#pragma unroll
      for (int dt = 0; dt < 4; ++dt) {
        const __bf16* vr = Vts + (dt * 16 + c) * 72 + quad * 8;
        bf16x8 b0 = *(const bf16x8*)vr;
        bf16x8 b1 = *(const bf16x8*)(vr + 32);
        o[dt] = mfma_bf16(ap0, b0, o[dt]);
        o[dt] = mfma_bf16(ap1, b1, o[dt]);
      }
    }
    __syncthreads();
  }

  // normalize + write [b][s][h*64+d] bf16
#pragma unroll
  for (int r = 0; r < 4; ++r) {
    const int s = q0 + wave * 16 + quad * 4 + r;
    const float inv_l = 1.0f / l_run[r];
#pragma unroll
    for (int dt = 0; dt < 4; ++dt) {
      AOb[((size_t)(b * S_LEN + s)) * DMODEL + h * DHEAD + dt * 16 + c] =
          (__bf16)(o[dt][r] * inv_l);
    }
  }
}

// ---------------------------------------------------------------- launch
extern "C" void kernel_launch(void* const* d_in, const int* in_sizes, int n_in,
                              void* d_out, int out_size, void* d_ws, size_t ws_size,
                              hipStream_t stream) {
  const float* x    = (const float*)d_in[0];
  const float* Wqkv = (const float*)d_in[1];
  const float* bqkv = (const float*)d_in[2];
  const float* Wout = (const float*)d_in[3];
  const float* bout = (const float*)d_in[4];
  float* out = (float*)d_out;

  char* ws = (char*)d_ws;
  __bf16* xb    = (__bf16*)(ws + 0);                    //  8 MB  (4096x1024)
  __bf16* Wqkvb = (__bf16*)(ws + (size_t)8  * 1024 * 1024);  // 6 MB (3072x1024)
  __bf16* Woutb = (__bf16*)(ws + (size_t)14 * 1024 * 1024);  // 2 MB (1024x1024)
  __bf16* Qb    = (__bf16*)(ws + (size_t)16 * 1024 * 1024);  // 8 MB [bh][s][d]
  __bf16* Kb    = (__bf16*)(ws + (size_t)24 * 1024 * 1024);  // 8 MB
  __bf16* Vb    = (__bf16*)(ws + (size_t)32 * 1024 * 1024);  // 8 MB
  __bf16* Vtb   = (__bf16*)(ws + (size_t)40 * 1024 * 1024);  // 8 MB [bh][d][s]
  __bf16* AOb   = (__bf16*)(ws + (size_t)48 * 1024 * 1024);  // 8 MB [b][s][dm]

  cvt_kernel<<<(TOK * DMODEL) / 1024, 256, 0, stream>>>(x, xb, TOK * DMODEL);
  cvt_kernel<<<(NQKV * DMODEL) / 1024, 256, 0, stream>>>(Wqkv, Wqkvb, NQKV * DMODEL);
  cvt_kernel<<<(DMODEL * DMODEL) / 1024, 256, 0, stream>>>(Wout, Woutb, DMODEL * DMODEL);

  gemm_qkv_kernel<<<dim3(NQKV / 128, TOK / 128), 256, 0, stream>>>(xb, Wqkvb, bqkv, Qb, Kb, Vb);

  rope_kernel<<<(2 * BH_TOT * S_LEN * 16) / 256, 256, 0, stream>>>(Qb, Kb);

  vtrans_kernel<<<BH_TOT * (S_LEN / 64), 256, 0, stream>>>(Vb, Vtb);

  attn_kernel<<<dim3(S_LEN / 64, BH_TOT), 256, 0, stream>>>(Qb, Kb, Vtb, AOb);

  gemm_out_kernel<<<dim3(DMODEL / 128, TOK / 128), 256, 0, stream>>>(AOb, Woutb, bout, out);
}

// Round 2
// 240.096 us; speedup vs baseline: 1.1292x; 1.1292x over previous
//
#include <hip/hip_runtime.h>

#define S_LEN 2048
#define DMODEL 1024
#define NHEAD 16
#define DHEAD 64
#define BATCH 2
#define BH_TOT (BATCH * NHEAD)   // 32
#define TOK (BATCH * S_LEN)      // 4096
#define NQKV (3 * DMODEL)        // 3072

// softmax scale 1/sqrt(64) = 0.125, fused with log2(e) so scores are in log2 domain
#define QSCALE 0.18033688011112042f

typedef float  f32x4  __attribute__((ext_vector_type(4)));
typedef __bf16 bf16x8 __attribute__((ext_vector_type(8)));
typedef __bf16 bf16x4 __attribute__((ext_vector_type(4)));
typedef __bf16 bf16x2 __attribute__((ext_vector_type(2)));

typedef __attribute__((address_space(1))) void* as1_ptr;
typedef __attribute__((address_space(3))) void* as3_ptr;

__device__ __forceinline__ void gl2lds16(const void* g, void* l) {
  __builtin_amdgcn_global_load_lds((as1_ptr)(void*)g, (as3_ptr)l, 16, 0, 0);
}

__device__ __forceinline__ f32x4 mfma_bf16(bf16x8 a, bf16x8 b, f32x4 c) {
  return __builtin_amdgcn_mfma_f32_16x16x32_bf16(a, b, c, 0, 0, 0);
}

// ---------------------------------------------------------------- convert f32 -> bf16
__global__ __launch_bounds__(256) void cvt_kernel(const float* __restrict__ src,
                                                  __bf16* __restrict__ dst, int n) {
  const int i = (blockIdx.x * 256 + threadIdx.x) * 4;
  if (i >= n) return;
  const f32x4 v = *(const f32x4*)(src + i);
  bf16x4 o;
  o[0] = (__bf16)v[0]; o[1] = (__bf16)v[1]; o[2] = (__bf16)v[2]; o[3] = (__bf16)v[3];
  *(bf16x4*)(dst + i) = o;
}

// ---------------------------------------------------------------- 128x128 bf16 GEMM mainloop
// C[128x128] = A_tile[128xK] * B_tile[128xK]^T  (both row-major [row][k], bf16)
__device__ __forceinline__ void gemm_tile_128(const __bf16* __restrict__ A,
                                              const __bf16* __restrict__ Bw,
                                              const int Kd, const int tileM, const int tileN,
                                              __bf16* As, __bf16* Bs, f32x4 acc[4][4]) {
  const int t    = threadIdx.x;
  const int lane = t & 63;
  const int wave = t >> 6;
  const int quad = lane >> 4;
  const int c    = lane & 15;
  const int wm   = (wave >> 1) << 6;
  const int wn   = (wave & 1) << 6;

  const int u0 = t, u1 = t + 256;
  const __bf16* gA0 = A  + (size_t)(tileM + (u0 >> 2)) * Kd + (u0 & 3) * 8;
  const __bf16* gA1 = A  + (size_t)(tileM + (u1 >> 2)) * Kd + (u1 & 3) * 8;
  const __bf16* gB0 = Bw + (size_t)(tileN + (u0 >> 2)) * Kd + (u0 & 3) * 8;
  const __bf16* gB1 = Bw + (size_t)(tileN + (u1 >> 2)) * Kd + (u1 & 3) * 8;
  __bf16* lA0 = As + u0 * 8; __bf16* lA1 = As + u1 * 8;
  __bf16* lB0 = Bs + u0 * 8; __bf16* lB1 = Bs + u1 * 8;

  for (int k0 = 0; k0 < Kd; k0 += 32) {
    gl2lds16(gA0 + k0, lA0);
    gl2lds16(gA1 + k0, lA1);
    gl2lds16(gB0 + k0, lB0);
    gl2lds16(gB1 + k0, lB1);
    __syncthreads();
    bf16x8 af[4], bfr[4];
#pragma unroll
    for (int mt = 0; mt < 4; ++mt)
      af[mt] = *(const bf16x8*)(As + (wm + mt * 16 + c) * 32 + quad * 8);
#pragma unroll
    for (int nt = 0; nt < 4; ++nt)
      bfr[nt] = *(const bf16x8*)(Bs + (wn + nt * 16 + c) * 32 + quad * 8);
#pragma unroll
    for (int mt = 0; mt < 4; ++mt)
#pragma unroll
      for (int nt = 0; nt < 4; ++nt)
        acc[mt][nt] = mfma_bf16(af[mt], bfr[nt], acc[mt][nt]);
    __syncthreads();
  }
}

// ---------------------------------------------------------------- QKV projection (+V transpose fused, +Q log2-scale)
__global__ __launch_bounds__(256) void gemm_qkv_kernel(const __bf16* __restrict__ xb,
                                                       const __bf16* __restrict__ Wb,
                                                       const float* __restrict__ bias,
                                                       __bf16* __restrict__ Qb,
                                                       __bf16* __restrict__ Kb,
                                                       __bf16* __restrict__ Vtb) {
  __shared__ __align__(16) __bf16 As[128 * 32];
  __shared__ __align__(16) __bf16 Bs[128 * 32];
  f32x4 acc[4][4];
#pragma unroll
  for (int i = 0; i < 4; ++i)
#pragma unroll
    for (int j = 0; j < 4; ++j) acc[i][j] = (f32x4){0.f, 0.f, 0.f, 0.f};

  const int tileM = blockIdx.y * 128;
  const int tileN = blockIdx.x * 128;
  gemm_tile_128(xb, Wb, DMODEL, tileM, tileN, As, Bs, acc);

  const int t = threadIdx.x;
  const int lane = t & 63, wave = t >> 6;
  const int quad = lane >> 4, c = lane & 15;
  const int wm = (wave >> 1) << 6, wn = (wave & 1) << 6;

#pragma unroll
  for (int nt = 0; nt < 4; ++nt) {
    const int col = tileN + wn + nt * 16 + c;
    const float bv = bias[col];
    const int which = col >> 10;         // 0=q,1=k,2=v  (uniform within 16-col group)
    const int h  = (col >> 6) & 15;
    const int dh = col & 63;
    if (which == 2) {
      // V: write directly transposed [bh][d][s], 4 consecutive tokens packed
#pragma unroll
      for (int mt = 0; mt < 4; ++mt) {
        const int row0 = tileM + wm + mt * 16 + quad * 4;   // token id of r=0
        const int bb = row0 >> 11;
        const int ss = row0 & (S_LEN - 1);
        bf16x4 o;
#pragma unroll
        for (int r = 0; r < 4; ++r) o[r] = (__bf16)(acc[mt][nt][r] + bv);
        *(bf16x4*)(Vtb + (((size_t)(bb * NHEAD + h)) * DHEAD + dh) * S_LEN + ss) = o;
      }
    } else {
      __bf16* dst = (which == 0) ? Qb : Kb;
      const float scl = (which == 0) ? QSCALE : 1.0f;
#pragma unroll
      for (int mt = 0; mt < 4; ++mt) {
#pragma unroll
        for (int r = 0; r < 4; ++r) {
          const int row = tileM + wm + mt * 16 + quad * 4 + r;
          const int bb = row >> 11;
          const int ss = row & (S_LEN - 1);
          dst[(((size_t)(bb * NHEAD + h)) * S_LEN + ss) * DHEAD + dh] =
              (__bf16)((acc[mt][nt][r] + bv) * scl);
        }
      }
    }
  }
}

// ---------------------------------------------------------------- output projection
__global__ __launch_bounds__(256) void gemm_out_kernel(const __bf16* __restrict__ AOb,
                                                       const __bf16* __restrict__ Wb,
                                                       const float* __restrict__ bout,
                                                       float* __restrict__ out) {
  __shared__ __align__(16) __bf16 As[128 * 32];
  __shared__ __align__(16) __bf16 Bs[128 * 32];
  f32x4 acc[4][4];
#pragma unroll
  for (int i = 0; i < 4; ++i)
#pragma unroll
    for (int j = 0; j < 4; ++j) acc[i][j] = (f32x4){0.f, 0.f, 0.f, 0.f};

  const int tileM = blockIdx.y * 128;
  const int tileN = blockIdx.x * 128;
  gemm_tile_128(AOb, Wb, DMODEL, tileM, tileN, As, Bs, acc);

  const int t = threadIdx.x;
  const int lane = t & 63, wave = t >> 6;
  const int quad = lane >> 4, c = lane & 15;
  const int wm = (wave >> 1) << 6, wn = (wave & 1) << 6;

#pragma unroll
  for (int nt = 0; nt < 4; ++nt) {
    const int col = tileN + wn + nt * 16 + c;
    const float bv = bout[col];
#pragma unroll
    for (int mt = 0; mt < 4; ++mt) {
#pragma unroll
      for (int r = 0; r < 4; ++r) {
        const int row = tileM + wm + mt * 16 + quad * 4 + r;
        out[(size_t)row * DMODEL + col] = acc[mt][nt][r] + bv;
      }
    }
  }
}

// ---------------------------------------------------------------- partial interleaved RoPE (in place on Q and K)
// Q is pre-scaled by QSCALE; rotation commutes with scalar scale.
__global__ __launch_bounds__(256) void rope_kernel(__bf16* __restrict__ Qb, __bf16* __restrict__ Kb) {
  const int idx = blockIdx.x * 256 + threadIdx.x;   // [0, 2*32*2048*16)
  const int j  = idx & 15;                          // rotation pair (dims 2j, 2j+1)
  const int s  = (idx >> 4) & (S_LEN - 1);
  const int bh = (idx >> 15) & (BH_TOT - 1);
  __bf16* base = (idx >> 20) ? Kb : Qb;
  bf16x2* p = (bf16x2*)(base + ((size_t)bh * S_LEN + s) * DHEAD) + j;
  bf16x2 v = *p;
  const float x1 = (float)v[0];
  const float x2 = (float)v[1];
  const float LOG2_10000 = 13.287712379549449f;
  const float inv = exp2f(-(float)j * (LOG2_10000 / 16.0f));
  const float ang = (float)s * inv;
  float sn, cs;
  sincosf(ang, &sn, &cs);
  bf16x2 o;
  o[0] = (__bf16)(x1 * cs - x2 * sn);
  o[1] = (__bf16)(x2 * cs + x1 * sn);
  *p = o;
}

// ---------------------------------------------------------------- flash attention, fully transposed orientation
// S^T = K·Q^T (per-lane q = lane&15), O^T = V^T·P^T. Softmax state scalar per lane.
// grid: x = q-tile (32), y = bh (32); block 256 = 4 waves, each wave owns 16 q-rows
__global__ __launch_bounds__(256) void attn_kernel(const __bf16* __restrict__ Qb,
                                                   const __bf16* __restrict__ Kb,
                                                   const __bf16* __restrict__ Vtb,
                                                   __bf16* __restrict__ AOb) {
  __shared__ __align__(16) __bf16 Ks[64 * 72];    // [key][d]
  __shared__ __align__(16) __bf16 Vts[64 * 72];   // [d][key]
  __shared__ __align__(16) __bf16 Ps[4][16 * 72]; // per-wave P strip [q][key]

  const int qt = blockIdx.x;
  const int bh = blockIdx.y;
  const int b = bh >> 4, h = bh & 15;
  const int t = threadIdx.x, wave = t >> 6, lane = t & 63;
  const int quad = lane >> 4, c = lane & 15;

  const size_t head = (size_t)bh * S_LEN * DHEAD;
  const int q0 = qt * 64;

  // Q fragment, used as the MFMA B-operand: B[k=quad*8+j][n=q=c]
  bf16x8 aq0, aq1;
  {
    const __bf16* qp = Qb + head + (size_t)(q0 + wave * 16 + c) * DHEAD + quad * 8;
    aq0 = *(const bf16x8*)qp;
    aq1 = *(const bf16x8*)(qp + 32);
  }

  float m_run = -1e30f, l_run = 0.f;
  f32x4 ot[4];   // O^T: lane holds q=c, d = dt*16 + quad*4 + r
#pragma unroll
  for (int dt = 0; dt < 4; ++dt) ot[dt] = (f32x4){0.f, 0.f, 0.f, 0.f};

  for (int kb = 0; kb < S_LEN / 64; ++kb) {
    const int k0 = kb * 64;
#pragma unroll
    for (int i = 0; i < 2; ++i) {
      const int u = t + i * 256;
      const int row = u >> 3, cc = u & 7;
      *(bf16x8*)(Ks + row * 72 + cc * 8) =
          *(const bf16x8*)(Kb + head + (size_t)(k0 + row) * DHEAD + cc * 8);
      *(bf16x8*)(Vts + row * 72 + cc * 8) =
          *(const bf16x8*)(Vtb + ((size_t)bh * DHEAD + row) * S_LEN + k0 + cc * 8);
    }
    __syncthreads();

    // S^T strip: lane holds S'[q=c][key = nt*16 + quad*4 + r] (log2-domain, Q pre-scaled)
    f32x4 st[4];
#pragma unroll
    for (int nt = 0; nt < 4; ++nt) {
      const __bf16* kr = Ks + (nt * 16 + c) * 72 + quad * 8;
      bf16x8 k0f = *(const bf16x8*)kr;
      bf16x8 k1f = *(const bf16x8*)(kr + 32);
      f32x4 z = (f32x4){0.f, 0.f, 0.f, 0.f};
      z = mfma_bf16(k0f, aq0, z);   // A = K (m=key), B = Q^T (n=q)
      z = mfma_bf16(k1f, aq1, z);
      st[nt] = z;
    }

    // online softmax, all per-lane (q=c): in-lane reduce 16, then 2 butterflies
    float mx = -1e30f;
#pragma unroll
    for (int nt = 0; nt < 4; ++nt)
#pragma unroll
      for (int r = 0; r < 4; ++r) mx = fmaxf(mx, st[nt][r]);
    mx = fmaxf(mx, __shfl_xor(mx, 16));
    mx = fmaxf(mx, __shfl_xor(mx, 32));
    const float m_new = fmaxf(m_run, mx);
    const float alpha = exp2f(m_run - m_new);

    float rs = 0.f;
    bf16x4 pk[4];
#pragma unroll
    for (int nt = 0; nt < 4; ++nt) {
#pragma unroll
      for (int r = 0; r < 4; ++r) {
        const float p = exp2f(st[nt][r] - m_new);
        rs += p;
        pk[nt][r] = (__bf16)p;
      }
      // keys nt*16+quad*4 .. +3 contiguous -> one b64 store
      *(bf16x4*)(&Ps[wave][c * 72 + nt * 16 + quad * 4]) = pk[nt];
    }
    rs += __shfl_xor(rs, 16);
    rs += __shfl_xor(rs, 32);
    l_run = l_run * alpha + rs;
    m_run = m_new;
#pragma unroll
    for (int dt = 0; dt < 4; ++dt) ot[dt] *= alpha;

    // O^T += V^T · P^T   (A = V^T from Vts, B = P^T from Ps — same-wave LDS roundtrip)
    {
      const __bf16* pr = &Ps[wave][c * 72 + quad * 8];
      bf16x8 bp0 = *(const bf16x8*)pr;
      bf16x8 bp1 = *(const bf16x8*)(pr + 32);
#pragma unroll
      for (int dt = 0; dt < 4; ++dt) {
        const __bf16* vr = Vts + (dt * 16 + c) * 72 + quad * 8;
        bf16x8 v0 = *(const bf16x8*)vr;
        bf16x8 v1 = *(const bf16x8*)(vr + 32);
        ot[dt] = mfma_bf16(v0, bp0, ot[dt]);
        ot[dt] = mfma_bf16(v1, bp1, ot[dt]);
      }
    }
    __syncthreads();
  }

  // epilogue: lane owns q=c -> s; d contiguous over r -> packed 8B stores
  const int s = q0 + wave * 16 + c;
  const float inv_l = 1.0f / l_run;
#pragma unroll
  for (int dt = 0; dt < 4; ++dt) {
    bf16x4 o;
#pragma unroll
    for (int r = 0; r < 4; ++r) o[r] = (__bf16)(ot[dt][r] * inv_l);
    *(bf16x4*)(AOb + ((size_t)(b * S_LEN + s)) * DMODEL + h * DHEAD + dt * 16 + quad * 4) = o;
  }
}

// ---------------------------------------------------------------- launch
extern "C" void kernel_launch(void* const* d_in, const int* in_sizes, int n_in,
                              void* d_out, int out_size, void* d_ws, size_t ws_size,
                              hipStream_t stream) {
  const float* x    = (const float*)d_in[0];
  const float* Wqkv = (const float*)d_in[1];
  const float* bqkv = (const float*)d_in[2];
  const float* Wout = (const float*)d_in[3];
  const float* bout = (const float*)d_in[4];
  float* out = (float*)d_out;

  char* ws = (char*)d_ws;
  __bf16* xb    = (__bf16*)(ws + 0);                          //  8 MB (4096x1024)
  __bf16* Wqkvb = (__bf16*)(ws + (size_t)8  * 1024 * 1024);   //  6 MB (3072x1024)
  __bf16* Woutb = (__bf16*)(ws + (size_t)14 * 1024 * 1024);   //  2 MB (1024x1024)
  __bf16* Qb    = (__bf16*)(ws + (size_t)16 * 1024 * 1024);   //  8 MB [bh][s][d] (pre-scaled)
  __bf16* Kb    = (__bf16*)(ws + (size_t)24 * 1024 * 1024);   //  8 MB [bh][s][d]
  __bf16* Vtb   = (__bf16*)(ws + (size_t)32 * 1024 * 1024);   //  8 MB [bh][d][s]
  __bf16* AOb   = (__bf16*)(ws + (size_t)40 * 1024 * 1024);   //  8 MB [b][s][dm]

  cvt_kernel<<<(TOK * DMODEL) / 1024, 256, 0, stream>>>(x, xb, TOK * DMODEL);
  cvt_kernel<<<(NQKV * DMODEL) / 1024, 256, 0, stream>>>(Wqkv, Wqkvb, NQKV * DMODEL);
  cvt_kernel<<<(DMODEL * DMODEL) / 1024, 256, 0, stream>>>(Wout, Woutb, DMODEL * DMODEL);

  gemm_qkv_kernel<<<dim3(NQKV / 128, TOK / 128), 256, 0, stream>>>(xb, Wqkvb, bqkv, Qb, Kb, Vtb);

  rope_kernel<<<(2 * BH_TOT * S_LEN * 16) / 256, 256, 0, stream>>>(Qb, Kb);

  attn_kernel<<<dim3(S_LEN / 64, BH_TOT), 256, 0, stream>>>(Qb, Kb, Vtb, AOb);

  gemm_out_kernel<<<dim3(DMODEL / 128, TOK / 128), 256, 0, stream>>>(AOb, Woutb, bout, out);
}